// Round 3
// baseline (429.193 us; speedup 1.0000x reference)
//
#include <hip/hip_runtime.h>
#include <hip/hip_bf16.h>
#include <math.h>

typedef unsigned short u16;
typedef __attribute__((ext_vector_type(8))) short short8;
typedef __attribute__((ext_vector_type(4))) float f32x4;

#define NTOK 8192
#define DMODEL 1024
#define FDIM 4096
#define NEXP 8
#define CAP 1536

__device__ __forceinline__ u16 f2bf(float f) {
  __hip_bfloat16 b = __float2bfloat16(f);
  u16 u;
  __builtin_memcpy(&u, &b, 2);
  return u;
}

// branchless exact-erf GELU (Abramowitz-Stegun 7.1.26, |err| <= 1.5e-7)
__device__ __forceinline__ float gelu_exact(float v) {
  float x = v * 0.70710678118654752f;
  float ax = fabsf(x);
  float t = __builtin_amdgcn_rcpf(1.0f + 0.3275911f * ax);
  float p =
      t * (0.254829592f +
           t * (-0.284496736f +
                t * (1.421413741f + t * (-1.453152027f + t * 1.061405429f))));
  float er = 1.0f - p * __expf(-ax * ax);
  er = copysignf(er, x);
  return 0.5f * v * (1.0f + er);
}

// async global->LDS DMA, 16B/lane. LDS dest = wave-uniform base + lane*16.
__device__ __forceinline__ void gload_lds16(const u16* g, u16* l) {
  __builtin_amdgcn_global_load_lds(
      (const __attribute__((address_space(1))) void*)g,
      (__attribute__((address_space(3))) void*)l, 16, 0, 0);
}

// ===== K1: router =====
__global__ __launch_bounds__(256) void router_kernel(
    const float* __restrict__ x, const float* __restrict__ rw,
    int* __restrict__ chosen_e, float* __restrict__ chosen_p) {
  int b = blockIdx.x, tid = threadIdx.x;
  int tok = (b * 256 + tid) >> 6;
  int lane = tid & 63;
  const float4* xp = (const float4*)(x + (size_t)tok * DMODEL) + lane * 4;
  float4 x0 = xp[0], x1 = xp[1], x2 = xp[2], x3 = xp[3];
  float l[8];
#pragma unroll
  for (int e = 0; e < 8; e++) {
    const float4* wp = (const float4*)(rw + (size_t)e * DMODEL) + lane * 4;
    float4 w0 = wp[0], w1v = wp[1], w2v = wp[2], w3 = wp[3];
    float s = x0.x * w0.x + x0.y * w0.y + x0.z * w0.z + x0.w * w0.w;
    s += x1.x * w1v.x + x1.y * w1v.y + x1.z * w1v.z + x1.w * w1v.w;
    s += x2.x * w2v.x + x2.y * w2v.y + x2.z * w2v.z + x2.w * w2v.w;
    s += x3.x * w3.x + x3.y * w3.y + x3.z * w3.z + x3.w * w3.w;
    l[e] = s;
  }
#pragma unroll
  for (int off = 32; off > 0; off >>= 1) {
#pragma unroll
    for (int e = 0; e < 8; e++) l[e] += __shfl_xor(l[e], off, 64);
  }
  if (lane == 0) {
    float best = l[0];
    int am = 0;
#pragma unroll
    for (int e = 1; e < 8; e++)
      if (l[e] > best) { best = l[e]; am = e; }
    float denom = 0.f;
#pragma unroll
    for (int e = 0; e < 8; e++) denom += expf(l[e] - best);
    chosen_e[tok] = am;
    chosen_p[tok] = 1.0f / denom;
  }
}

// 256x256 fp32->bf16 transpose tile through swizzled LDS, 1024 threads.
// Output K-BLOCKED: out[inner/32][outer][inner%32].
__device__ __forceinline__ void trans256(const float* __restrict__ ip,
                                         u16* __restrict__ op, int Rin,
                                         int Cin, int r0, int c0, char* lds,
                                         int tid) {
  int w = tid >> 6, l = tid & 63;
#pragma unroll
  for (int i = 0; i < 16; i++) {
    int row = w * 16 + i;
    float4 v = *(const float4*)(ip + (size_t)(r0 + row) * Cin + c0 + l * 4);
    uint2 d;
    d.x = (unsigned)f2bf(v.x) | ((unsigned)f2bf(v.y) << 16);
    d.y = (unsigned)f2bf(v.z) | ((unsigned)f2bf(v.w) << 16);
    int ch = (l >> 1) ^ ((row >> 3) & 7);
    *(uint2*)(lds + row * 512 + ch * 16 + (l & 1) * 8) = d;
  }
  __syncthreads();
#pragma unroll
  for (int p = 0; p < 2; p++) {
    int c = ((tid >> 5) + p * 32) * 4;
    int rb = (tid & 31) * 8;
    short8 s0, s1, s2, s3;
#pragma unroll
    for (int j = 0; j < 8; j++) {
      int r = rb + j;
      int ch = (c >> 3) ^ ((r >> 3) & 7);
      uint2 d = *(const uint2*)(lds + r * 512 + ch * 16 + (c & 7) * 2);
      s0[j] = (short)(d.x & 0xffff);
      s1[j] = (short)(d.x >> 16);
      s2[j] = (short)(d.y & 0xffff);
      s3[j] = (short)(d.y >> 16);
    }
    u16* ob = op + (size_t)((r0 + rb) >> 5) * Cin * 32 +
              (size_t)(c0 + c) * 32 + ((r0 + rb) & 31);
    *(short8*)(ob) = s0;
    *(short8*)(ob + 32) = s1;
    *(short8*)(ob + 64) = s2;
    *(short8*)(ob + 96) = s3;
  }
}

// ===== K2: scan (block 0) + w1/w2 transpose =====
__global__ __launch_bounds__(1024, 1) void wtrans_kernel(
    const float* __restrict__ w1, const float* __restrict__ w2,
    u16* __restrict__ w1t, u16* __restrict__ w2t,
    const int* __restrict__ chosen_e, int* __restrict__ tok_of_slot,
    int* __restrict__ counts, float* __restrict__ out) {
  extern __shared__ char lds[];
  int b = blockIdx.x, tid = threadIdx.x;
  if (b == 0) {
    if (tid < 512) {
      int w = tid >> 6, lane = tid & 63;
      unsigned long long ltmask =
          (lane == 63) ? ~0ull >> 1 : (1ull << lane) - 1ull;
      int cnt = 0;
      for (int c = 0; c < NTOK / 64; c++) {
        int i = c * 64 + lane;
        int e = chosen_e[i];
        unsigned long long bal = __ballot(e == w);
        if (e == w) {
          int p = cnt + __popcll(bal & ltmask);
          if (p < CAP) {
            tok_of_slot[w * CAP + p] = i;
          } else {
            float4 z = make_float4(0.f, 0.f, 0.f, 0.f);
            float* orow = out + (size_t)i * DMODEL;
            for (int d = 0; d < DMODEL; d += 4) *(float4*)(orow + d) = z;
          }
        }
        cnt += __popcll(bal);
      }
      for (int p = cnt + lane; p < CAP; p += 64) tok_of_slot[w * CAP + p] = -1;
      if (lane == 0) counts[w] = cnt < CAP ? cnt : CAP;
    }
  } else if (b < 513) {
    int idx = b - 1;
    int e = idx >> 6, rem = idx & 63;
    int r0 = (rem >> 4) * 256, c0 = (rem & 15) * 256;
    trans256(w1 + (size_t)e * DMODEL * FDIM, w1t + (size_t)e * DMODEL * FDIM,
             DMODEL, FDIM, r0, c0, lds, tid);
  } else {
    int idx = b - 513;
    int e = idx >> 6, rem = idx & 63;
    int r0 = (rem >> 2) * 256, c0 = (rem & 3) * 256;
    trans256(w2 + (size_t)e * DMODEL * FDIM, w2t + (size_t)e * DMODEL * FDIM,
             FDIM, DMODEL, r0, c0, lds, tid);
  }
}

// ===== K2.5: gather chosen tokens into dense xg[e*CAP+slot][D] (bf16) =====
__global__ __launch_bounds__(256) void gather_kernel(
    const float* __restrict__ x, const int* __restrict__ tok_of_slot,
    u16* __restrict__ xg) {
  int slot = blockIdx.x * 4 + (threadIdx.x >> 6);
  int lane = threadIdx.x & 63;
  int tok = tok_of_slot[slot];
  u16* dst = xg + (size_t)slot * DMODEL + lane * 16;
  if (tok < 0) {
    short8 z = {};
    *(short8*)(dst) = z;
    *(short8*)(dst + 8) = z;
    return;
  }
  const float4* sp = (const float4*)(x + (size_t)tok * DMODEL) + lane * 4;
  float4 a = sp[0], b = sp[1], c = sp[2], d = sp[3];
  short8 s0, s1;
  s0[0] = (short)f2bf(a.x); s0[1] = (short)f2bf(a.y);
  s0[2] = (short)f2bf(a.z); s0[3] = (short)f2bf(a.w);
  s0[4] = (short)f2bf(b.x); s0[5] = (short)f2bf(b.y);
  s0[6] = (short)f2bf(b.z); s0[7] = (short)f2bf(b.w);
  s1[0] = (short)f2bf(c.x); s1[1] = (short)f2bf(c.y);
  s1[2] = (short)f2bf(c.z); s1[3] = (short)f2bf(c.w);
  s1[4] = (short)f2bf(d.x); s1[5] = (short)f2bf(d.y);
  s1[6] = (short)f2bf(d.z); s1[7] = (short)f2bf(d.w);
  *(short8*)(dst) = s0;
  *(short8*)(dst + 8) = s1;
}

// ---------------- XCD-aware bijective tile swizzle (nwg % 8 == 0) ------------
template <int NX, int NY>
__device__ __forceinline__ void tile_coords(int& bx, int& by, int& bz) {
  int flat = blockIdx.x + NX * (blockIdx.y + NY * blockIdx.z);
  int nwg = NX * NY * (int)gridDim.z;
  int swz = (flat & 7) * (nwg >> 3) + (flat >> 3);
  bx = swz % NX;
  int rem = swz / NX;
  by = rem % NY;
  bz = rem / NY;
}

// ------- GEMM1: 256x256 tile, BK=32; A via LDS (dbuf), B direct->regs --------
// 512 thr = 8 waves as 4M x 2N (per-wave 64x128, acc[4][8]).
// B-frags load coalesced from K-blocked w1t (1KB/wave-instr); B-side LDS
// traffic eliminated; A multiplicity drops to 2x. LDS 64KB: mainloop uses
// 32KB (2 x 16KB A tiles), epilogue reuses 64KB as 128x256 bf16 C image.
template <int NX, int NY>
__global__ __launch_bounds__(512, 2) void gemm1_kernel(
    const u16* __restrict__ xg, const u16* __restrict__ w1tB,
    const int* __restrict__ counts, u16* __restrict__ hB,
    const float* __restrict__ b1, int e0, long long hStrideE) {
  extern __shared__ __align__(16) u16 smem[];  // 32768 u16 = 64 KB
  int bx, by, bz;
  tile_coords<NX, NY>(bx, by, bz);
  int e = e0 + bz;
  int m0 = by * 256, n0 = bx * 256;
  if (m0 >= counts[e]) return;
  const u16* Bg = w1tB + (size_t)e * FDIM * DMODEL;
  u16* H = hB + (size_t)bz * hStrideE;
  int tid = threadIdx.x;

  // A staging: rows m0..m0+255 of xg, [256][32] LDS tiles
  int r4 = tid >> 2, c8 = (tid & 3) * 8;
  const u16* pa0 = xg + (size_t)(e * CAP + m0 + r4) * DMODEL + c8;
  const u16* pa1 = pa0 + (size_t)128 * DMODEL;

  int wid = tid >> 6, lane = tid & 63;
  int wm = (wid >> 1) * 64, wn = (wid & 1) * 128;
  int fr = lane & 15, fkb = (lane >> 4) * 8;
  int aoff = (wm + fr) * 32 + fkb;
  // B-frag base: K-blocked w1t[kb][f][32]; wave reads 1KB contiguous per frag
  const u16* Bcol = Bg + (size_t)(n0 + wn + fr) * 32 + fkb;

  f32x4 acc[4][8] = {};
  short8 bA[8], bB[8];

  auto stageA = [&](int t, int buf) {
    u16* d = smem + buf * 8192 + tid * 8;
    gload_lds16(pa0 + t * 32, d);
    gload_lds16(pa1 + t * 32, d + 4096);
  };
  auto loadB = [&](short8(&bd)[8], int t) {
    const u16* p = Bcol + (size_t)t * (FDIM * 32);
#pragma unroll
    for (int n = 0; n < 8; n++) bd[n] = *(const short8*)(p + n * 512);
  };
  auto compute = [&](int buf, short8(&bd)[8]) {
    const u16* cb = smem + buf * 8192;
    short8 av[4];
#pragma unroll
    for (int m = 0; m < 4; m++) av[m] = *(const short8*)(cb + aoff + m * 512);
#pragma unroll
    for (int m = 0; m < 4; m++)
#pragma unroll
      for (int n = 0; n < 8; n++)
        acc[m][n] = __builtin_amdgcn_mfma_f32_16x16x32_bf16(av[m], bd[n],
                                                            acc[m][n], 0, 0, 0);
  };

  stageA(0, 0);
  loadB(bA, 0);
  __syncthreads();
#pragma unroll 1
  for (int t = 0; t < DMODEL / 32; t += 2) {
    if (t + 1 < DMODEL / 32) {
      stageA(t + 1, 1);
      loadB(bB, t + 1);
    }
    compute(0, bA);
    __syncthreads();
    if (t + 2 < DMODEL / 32) {
      stageA(t + 2, 0);
      loadB(bA, t + 2);
    }
    compute(1, bB);
    __syncthreads();
  }

  // epilogue: bias + GELU -> swizzled 128x256 LDS image, 2 rounds
  int fq = lane >> 4;
  const float* b1g = b1 + (size_t)e * FDIM + n0;
  float bias[8];
#pragma unroll
  for (int n = 0; n < 8; n++) bias[n] = b1g[wn + n * 16 + fr];
#pragma unroll
  for (int half = 0; half < 2; half++) {
    if ((wid >> 2) == half) {  // wid 0-3: rows 0-127; wid 4-7: rows 128-255
      int rbase = wm & 127;
#pragma unroll
      for (int m = 0; m < 4; m++) {
#pragma unroll
        for (int n = 0; n < 8; n++) {
          int colL = wn + n * 16 + fr;
#pragma unroll
          for (int j = 0; j < 4; j++) {
            int rL = rbase + m * 16 + fq * 4 + j;
            float v = gelu_exact(acc[m][n][j] + bias[n]);
            int ch = (colL >> 3) ^ ((rL >> 2) & 7);
            smem[rL * 256 + ch * 8 + (colL & 7)] = f2bf(v);
          }
        }
      }
    }
    __syncthreads();
#pragma unroll
    for (int p = 0; p < 8; p++) {
      int idx = p * 512 + tid;
      int rr = idx >> 5, cch = idx & 31;
      int ch = cch ^ ((rr >> 2) & 7);
      short8 v = *(const short8*)(smem + rr * 256 + ch * 8);
      *(short8*)(H + (size_t)(m0 + half * 128 + rr) * FDIM + n0 + cch * 8) = v;
    }
    __syncthreads();
  }
}

// ------- GEMM2: 128x128 tile, BK=32; A via LDS (dbuf), B direct->regs --------
// 256 thr = 4 waves as 2M x 2N (per-wave 64x64, acc[4][4]). LDS 16KB.
template <int NX, int NY>
__global__ __launch_bounds__(256, 2) void gemm2_kernel(
    const u16* __restrict__ hB, const u16* __restrict__ w2tB,
    float* __restrict__ out, const float* __restrict__ b2,
    const int* __restrict__ tok_of_slot, const int* __restrict__ counts,
    const float* __restrict__ chosen_p, int e0, long long hStrideE) {
  __shared__ __align__(16) u16 smem[8192];  // 2 x 8KB A tiles
  int bx, by, bz;
  tile_coords<NX, NY>(bx, by, bz);
  int e = e0 + bz;
  int m0 = by * 128, n0 = bx * 128;
  if (m0 >= counts[e]) return;
  const u16* Ag = hB + (size_t)bz * hStrideE;
  const u16* Bg = w2tB + (size_t)e * DMODEL * FDIM;
  const float* b2g = b2 + (size_t)e * DMODEL;
  int tid = threadIdx.x;

  int r4 = tid >> 2, c8 = (tid & 3) * 8;
  const u16* pa0 = Ag + (size_t)(m0 + r4) * FDIM + c8;
  const u16* pa1 = pa0 + (size_t)64 * FDIM;

  int wid = tid >> 6, lane = tid & 63;
  int wm = (wid >> 1) * 64, wn = (wid & 1) * 64;
  int fr = lane & 15, fkb = (lane >> 4) * 8;
  int aoff = (wm + fr) * 32 + fkb;
  const u16* Bcol = Bg + (size_t)(n0 + wn + fr) * 32 + fkb;

  f32x4 acc[4][4] = {};
  short8 bA[4], bB[4];

  auto stageA = [&](int t, int buf) {
    u16* d = smem + buf * 4096 + tid * 8;
    gload_lds16(pa0 + t * 32, d);
    gload_lds16(pa1 + t * 32, d + 2048);
  };
  auto loadB = [&](short8(&bd)[4], int t) {
    const u16* p = Bcol + (size_t)t * (DMODEL * 32);
#pragma unroll
    for (int n = 0; n < 4; n++) bd[n] = *(const short8*)(p + n * 512);
  };
  auto compute = [&](int buf, short8(&bd)[4]) {
    const u16* cb = smem + buf * 4096;
    short8 av[4];
#pragma unroll
    for (int m = 0; m < 4; m++) av[m] = *(const short8*)(cb + aoff + m * 512);
#pragma unroll
    for (int m = 0; m < 4; m++)
#pragma unroll
      for (int n = 0; n < 4; n++)
        acc[m][n] = __builtin_amdgcn_mfma_f32_16x16x32_bf16(av[m], bd[n],
                                                            acc[m][n], 0, 0, 0);
  };

  stageA(0, 0);
  loadB(bA, 0);
  __syncthreads();
#pragma unroll 1
  for (int t = 0; t < FDIM / 32; t += 2) {
    if (t + 1 < FDIM / 32) {
      stageA(t + 1, 1);
      loadB(bB, t + 1);
    }
    compute(0, bA);
    __syncthreads();
    if (t + 2 < FDIM / 32) {
      stageA(t + 2, 0);
      loadB(bA, t + 2);
    }
    compute(1, bB);
    __syncthreads();
  }

  int fq = lane >> 4;
  float bias[4];
#pragma unroll
  for (int n = 0; n < 4; n++) bias[n] = b2g[n0 + wn + n * 16 + fr];
#pragma unroll
  for (int m = 0; m < 4; m++) {
#pragma unroll
    for (int j = 0; j < 4; j++) {
      int rL = wm + m * 16 + fq * 4 + j;
      int tk = tok_of_slot[e * CAP + m0 + rL];
      if (tk >= 0) {
        float sc = chosen_p[tk];
#pragma unroll
        for (int n = 0; n < 4; n++) {
          int colL = wn + n * 16 + fr;
          out[(size_t)tk * DMODEL + n0 + colL] = (acc[m][n][j] + bias[n]) * sc;
        }
      }
    }
  }
}

extern "C" void kernel_launch(void* const* d_in, const int* in_sizes, int n_in,
                              void* d_out, int out_size, void* d_ws,
                              size_t ws_size, hipStream_t stream) {
  const float* x = (const float*)d_in[0];
  const float* rw = (const float*)d_in[1];
  const float* w1 = (const float*)d_in[2];
  const float* b1 = (const float*)d_in[3];
  const float* w2 = (const float*)d_in[4];
  const float* b2 = (const float*)d_in[5];
  float* out = (float*)d_out;

  char* ws = (char*)d_ws;
  size_t off = 0;
  auto alloc = [&](size_t bytes) -> void* {
    void* p = ws + off;
    off = (off + bytes + 255) & ~(size_t)255;
    return p;
  };
  int* chosen_e = (int*)alloc((size_t)NTOK * 4);
  float* chosen_p = (float*)alloc((size_t)NTOK * 4);
  int* tok_of_slot = (int*)alloc((size_t)NEXP * CAP * 4);
  int* counts = (int*)alloc(NEXP * 4);
  u16* xg = (u16*)alloc((size_t)NEXP * CAP * DMODEL * 2);
  u16* w1t = (u16*)alloc((size_t)NEXP * DMODEL * FDIM * 2);
  u16* w2t = (u16*)alloc((size_t)NEXP * DMODEL * FDIM * 2);
  size_t hFull = (size_t)NEXP * CAP * FDIM * 2;
  size_t hLoop = (size_t)CAP * FDIM * 2;
  bool full = (off + hFull) <= ws_size;
  u16* h = (u16*)alloc(full ? hFull : hLoop);

  static_assert(CAP % 256 == 0 && FDIM % 256 == 0 && DMODEL % 128 == 0, "");
  const int TLDS = 131072, G1LDS = 65536;
  hipFuncSetAttribute((const void*)wtrans_kernel,
                      hipFuncAttributeMaxDynamicSharedMemorySize, TLDS);
  hipFuncSetAttribute((const void*)gemm1_kernel<FDIM / 256, CAP / 256>,
                      hipFuncAttributeMaxDynamicSharedMemorySize, G1LDS);

  router_kernel<<<NTOK / 4, 256, 0, stream>>>(x, rw, chosen_e, chosen_p);
  wtrans_kernel<<<1025, 1024, TLDS, stream>>>(w1, w2, w1t, w2t, chosen_e,
                                              tok_of_slot, counts, out);
  gather_kernel<<<NEXP * CAP / 4, 256, 0, stream>>>(x, tok_of_slot, xg);

  if (full) {
    gemm1_kernel<FDIM / 256, CAP / 256>
        <<<dim3(FDIM / 256, CAP / 256, NEXP), 512, G1LDS, stream>>>(
            xg, w1t, counts, h, b1, 0, (long long)CAP * FDIM);
    gemm2_kernel<DMODEL / 128, CAP / 128>
        <<<dim3(DMODEL / 128, CAP / 128, NEXP), 256, 0, stream>>>(
            h, w2t, out, b2, tok_of_slot, counts, chosen_p, 0,
            (long long)CAP * FDIM);
  } else {
    for (int e = 0; e < NEXP; e++) {
      gemm1_kernel<FDIM / 256, CAP / 256>
          <<<dim3(FDIM / 256, CAP / 256, 1), 512, G1LDS, stream>>>(
              xg, w1t, counts, h, b1, e, 0);
      gemm2_kernel<DMODEL / 128, CAP / 128>
          <<<dim3(DMODEL / 128, CAP / 128, 1), 256, 0, stream>>>(
              h, w2t, out, b2, tok_of_slot, counts, chosen_p, e, 0);
    }
  }
  (void)in_sizes;
  (void)n_in;
  (void)ws_size;
}

// Round 4
// 375.553 us; speedup vs baseline: 1.1428x; 1.1428x over previous
//
#include <hip/hip_runtime.h>
#include <hip/hip_bf16.h>
#include <math.h>

typedef unsigned short u16;
typedef __attribute__((ext_vector_type(8))) short short8;
typedef __attribute__((ext_vector_type(4))) float f32x4;

#define NTOK 8192
#define DMODEL 1024
#define FDIM 4096
#define NEXP 8
#define CAP 1536

__device__ __forceinline__ u16 f2bf(float f) {
  __hip_bfloat16 b = __float2bfloat16(f);
  u16 u;
  __builtin_memcpy(&u, &b, 2);
  return u;
}

// branchless exact-erf GELU (Abramowitz-Stegun 7.1.26, |err| <= 1.5e-7)
__device__ __forceinline__ float gelu_exact(float v) {
  float x = v * 0.70710678118654752f;
  float ax = fabsf(x);
  float t = __builtin_amdgcn_rcpf(1.0f + 0.3275911f * ax);
  float p =
      t * (0.254829592f +
           t * (-0.284496736f +
                t * (1.421413741f + t * (-1.453152027f + t * 1.061405429f))));
  float er = 1.0f - p * __expf(-ax * ax);
  er = copysignf(er, x);
  return 0.5f * v * (1.0f + er);
}

// async global->LDS DMA, 16B/lane. LDS dest = wave-uniform base + lane*16.
__device__ __forceinline__ void gload_lds16(const u16* g, u16* l) {
  __builtin_amdgcn_global_load_lds(
      (const __attribute__((address_space(1))) void*)g,
      (__attribute__((address_space(3))) void*)l, 16, 0, 0);
}

#define VMWAIT(N) asm volatile("s_waitcnt vmcnt(" #N ")" ::: "memory")
#define LGKM0 asm volatile("s_waitcnt lgkmcnt(0)" ::: "memory")
#define SB0 __builtin_amdgcn_sched_barrier(0)
#define BAR __builtin_amdgcn_s_barrier()

// ===== K1: router =====
__global__ __launch_bounds__(256) void router_kernel(
    const float* __restrict__ x, const float* __restrict__ rw,
    int* __restrict__ chosen_e, float* __restrict__ chosen_p) {
  int b = blockIdx.x, tid = threadIdx.x;
  int tok = (b * 256 + tid) >> 6;
  int lane = tid & 63;
  const float4* xp = (const float4*)(x + (size_t)tok * DMODEL) + lane * 4;
  float4 x0 = xp[0], x1 = xp[1], x2 = xp[2], x3 = xp[3];
  float l[8];
#pragma unroll
  for (int e = 0; e < 8; e++) {
    const float4* wp = (const float4*)(rw + (size_t)e * DMODEL) + lane * 4;
    float4 w0 = wp[0], w1v = wp[1], w2v = wp[2], w3 = wp[3];
    float s = x0.x * w0.x + x0.y * w0.y + x0.z * w0.z + x0.w * w0.w;
    s += x1.x * w1v.x + x1.y * w1v.y + x1.z * w1v.z + x1.w * w1v.w;
    s += x2.x * w2v.x + x2.y * w2v.y + x2.z * w2v.z + x2.w * w2v.w;
    s += x3.x * w3.x + x3.y * w3.y + x3.z * w3.z + x3.w * w3.w;
    l[e] = s;
  }
#pragma unroll
  for (int off = 32; off > 0; off >>= 1) {
#pragma unroll
    for (int e = 0; e < 8; e++) l[e] += __shfl_xor(l[e], off, 64);
  }
  if (lane == 0) {
    float best = l[0];
    int am = 0;
#pragma unroll
    for (int e = 1; e < 8; e++)
      if (l[e] > best) { best = l[e]; am = e; }
    float denom = 0.f;
#pragma unroll
    for (int e = 0; e < 8; e++) denom += expf(l[e] - best);
    chosen_e[tok] = am;
    chosen_p[tok] = 1.0f / denom;
  }
}

// 256x256 fp32->bf16 transpose tile through swizzled LDS, 1024 threads.
// Output K-BLOCKED: out[inner/32][outer][inner%32].
__device__ __forceinline__ void trans256(const float* __restrict__ ip,
                                         u16* __restrict__ op, int Rin,
                                         int Cin, int r0, int c0, char* lds,
                                         int tid) {
  int w = tid >> 6, l = tid & 63;
#pragma unroll
  for (int i = 0; i < 16; i++) {
    int row = w * 16 + i;
    float4 v = *(const float4*)(ip + (size_t)(r0 + row) * Cin + c0 + l * 4);
    uint2 d;
    d.x = (unsigned)f2bf(v.x) | ((unsigned)f2bf(v.y) << 16);
    d.y = (unsigned)f2bf(v.z) | ((unsigned)f2bf(v.w) << 16);
    int ch = (l >> 1) ^ ((row >> 3) & 7);
    *(uint2*)(lds + row * 512 + ch * 16 + (l & 1) * 8) = d;
  }
  __syncthreads();
#pragma unroll
  for (int p = 0; p < 2; p++) {
    int c = ((tid >> 5) + p * 32) * 4;
    int rb = (tid & 31) * 8;
    short8 s0, s1, s2, s3;
#pragma unroll
    for (int j = 0; j < 8; j++) {
      int r = rb + j;
      int ch = (c >> 3) ^ ((r >> 3) & 7);
      uint2 d = *(const uint2*)(lds + r * 512 + ch * 16 + (c & 7) * 2);
      s0[j] = (short)(d.x & 0xffff);
      s1[j] = (short)(d.x >> 16);
      s2[j] = (short)(d.y & 0xffff);
      s3[j] = (short)(d.y >> 16);
    }
    u16* ob = op + (size_t)((r0 + rb) >> 5) * Cin * 32 +
              (size_t)(c0 + c) * 32 + ((r0 + rb) & 31);
    *(short8*)(ob) = s0;
    *(short8*)(ob + 32) = s1;
    *(short8*)(ob + 64) = s2;
    *(short8*)(ob + 96) = s3;
  }
}

// ===== K2: scan (block 0) + w1/w2 transpose =====
__global__ __launch_bounds__(1024, 1) void wtrans_kernel(
    const float* __restrict__ w1, const float* __restrict__ w2,
    u16* __restrict__ w1t, u16* __restrict__ w2t,
    const int* __restrict__ chosen_e, int* __restrict__ tok_of_slot,
    int* __restrict__ counts, float* __restrict__ out) {
  extern __shared__ char lds[];
  int b = blockIdx.x, tid = threadIdx.x;
  if (b == 0) {
    if (tid < 512) {
      int w = tid >> 6, lane = tid & 63;
      unsigned long long ltmask =
          (lane == 63) ? ~0ull >> 1 : (1ull << lane) - 1ull;
      int cnt = 0;
      for (int c = 0; c < NTOK / 64; c++) {
        int i = c * 64 + lane;
        int e = chosen_e[i];
        unsigned long long bal = __ballot(e == w);
        if (e == w) {
          int p = cnt + __popcll(bal & ltmask);
          if (p < CAP) {
            tok_of_slot[w * CAP + p] = i;
          } else {
            float4 z = make_float4(0.f, 0.f, 0.f, 0.f);
            float* orow = out + (size_t)i * DMODEL;
            for (int d = 0; d < DMODEL; d += 4) *(float4*)(orow + d) = z;
          }
        }
        cnt += __popcll(bal);
      }
      for (int p = cnt + lane; p < CAP; p += 64) tok_of_slot[w * CAP + p] = -1;
      if (lane == 0) counts[w] = cnt < CAP ? cnt : CAP;
    }
  } else if (b < 513) {
    int idx = b - 1;
    int e = idx >> 6, rem = idx & 63;
    int r0 = (rem >> 4) * 256, c0 = (rem & 15) * 256;
    trans256(w1 + (size_t)e * DMODEL * FDIM, w1t + (size_t)e * DMODEL * FDIM,
             DMODEL, FDIM, r0, c0, lds, tid);
  } else {
    int idx = b - 513;
    int e = idx >> 6, rem = idx & 63;
    int r0 = (rem >> 2) * 256, c0 = (rem & 3) * 256;
    trans256(w2 + (size_t)e * DMODEL * FDIM, w2t + (size_t)e * DMODEL * FDIM,
             FDIM, DMODEL, r0, c0, lds, tid);
  }
}

// ===== K2.5: gather chosen tokens into dense xg[e*CAP+slot][D] (bf16) =====
__global__ __launch_bounds__(256) void gather_kernel(
    const float* __restrict__ x, const int* __restrict__ tok_of_slot,
    u16* __restrict__ xg) {
  int slot = blockIdx.x * 4 + (threadIdx.x >> 6);
  int lane = threadIdx.x & 63;
  int tok = tok_of_slot[slot];
  u16* dst = xg + (size_t)slot * DMODEL + lane * 16;
  if (tok < 0) {
    short8 z = {};
    *(short8*)(dst) = z;
    *(short8*)(dst + 8) = z;
    return;
  }
  const float4* sp = (const float4*)(x + (size_t)tok * DMODEL) + lane * 4;
  float4 a = sp[0], b = sp[1], c = sp[2], d = sp[3];
  short8 s0, s1;
  s0[0] = (short)f2bf(a.x); s0[1] = (short)f2bf(a.y);
  s0[2] = (short)f2bf(a.z); s0[3] = (short)f2bf(a.w);
  s0[4] = (short)f2bf(b.x); s0[5] = (short)f2bf(b.y);
  s0[6] = (short)f2bf(b.z); s0[7] = (short)f2bf(b.w);
  s1[0] = (short)f2bf(c.x); s1[1] = (short)f2bf(c.y);
  s1[2] = (short)f2bf(c.z); s1[3] = (short)f2bf(c.w);
  s1[4] = (short)f2bf(d.x); s1[5] = (short)f2bf(d.y);
  s1[6] = (short)f2bf(d.z); s1[7] = (short)f2bf(d.w);
  *(short8*)(dst) = s0;
  *(short8*)(dst + 8) = s1;
}

// ---------------- XCD-aware bijective tile swizzle (nwg % 8 == 0) ------------
template <int NX, int NY>
__device__ __forceinline__ void tile_coords(int& bx, int& by, int& bz) {
  int flat = blockIdx.x + NX * (blockIdx.y + NY * blockIdx.z);
  int nwg = NX * NY * (int)gridDim.z;
  int swz = (flat & 7) * (nwg >> 3) + (flat >> 3);
  bx = swz % NX;
  int rem = swz / NX;
  by = rem % NY;
  bz = rem / NY;
}

// ======= GEMM1: 256x256, BK=64 (2x kk-sub-blocks [256][32]), 4-phase =========
// 512 thr = 8 waves 2M x 4N (per-wave 128x64, acc[8][4]).
// LDS 128KB = 2 bufs x {A[2][256][32] + B[2][256][32]}. Per K-step, 4 phases:
//   P1:{ds a0-7/b01 kk0 | stage A-kk0(t+1)} P2:{ds b23 kk0 | stage B-kk0(t+1)}
//   P3:{ds kk1 | stage A-kk1(t+1)}          P4:{ds b23 kk1 | stage B-kk1(t+1)}
// each phase: barrier; lgkm0; 16 MFMA. vmcnt(4) BEFORE the P2/P4 barriers:
// retires exactly the kk-half the next 2 phases read; barrier join makes
// cross-wave DMA writes visible. Never vmcnt(0) in steady state.
#define G1_STAGE_A(t, kk)                                           \
  {                                                                 \
    u16* d_ = smem + ((t)&1) * 32768 + (kk)*8192 + tid * 8;         \
    const u16* s_ = paA + (size_t)(t)*64 + (kk)*32;                 \
    gload_lds16(s_, d_);                                            \
    gload_lds16(s_ + (size_t)128 * DMODEL, d_ + 4096);              \
  }
#define G1_STAGE_B(t, kk)                                           \
  {                                                                 \
    u16* d_ = smem + ((t)&1) * 32768 + 16384 + (kk)*8192 + tid * 8; \
    const u16* s_ = paB + (size_t)(2 * (t) + (kk)) * (FDIM * 32);   \
    gload_lds16(s_, d_);                                            \
    gload_lds16(s_ + 4096, d_ + 4096);                              \
  }
#define G1_LDA(kk)                                                  \
  _Pragma("unroll") for (int m_ = 0; m_ < 8; m_++) a_[m_] =         \
      *(const short8*)(smem + bufo + (kk)*8192 + aoff + m_ * 512);
#define G1_LDB(kk, n, dst)                                          \
  dst = *(const short8*)(smem + bufo + 16384 + (kk)*8192 + boff + (n)*512);
#define G1_MFMA(B0, B1, c0, c1)                                             \
  __builtin_amdgcn_s_setprio(1);                                            \
  _Pragma("unroll") for (int m_ = 0; m_ < 8; m_++) {                        \
    acc[m_][c0] = __builtin_amdgcn_mfma_f32_16x16x32_bf16(a_[m_], B0,       \
                                                          acc[m_][c0], 0,   \
                                                          0, 0);            \
    acc[m_][c1] = __builtin_amdgcn_mfma_f32_16x16x32_bf16(a_[m_], B1,       \
                                                          acc[m_][c1], 0,   \
                                                          0, 0);            \
  }                                                                         \
  __builtin_amdgcn_s_setprio(0);

#define G1_STEP(t, DO_STAGE, W2, W4)                                \
  {                                                                 \
    const int bufo = ((t)&1) * 32768;                               \
    short8 a_[8], b0_, b1_;                                         \
    G1_LDA(0); G1_LDB(0, 0, b0_); G1_LDB(0, 1, b1_);                \
    if (DO_STAGE) G1_STAGE_A((t) + 1, 0);                           \
    BAR; LGKM0; SB0;                                                \
    G1_MFMA(b0_, b1_, 0, 1);                                        \
    BAR;                                                            \
    G1_LDB(0, 2, b0_); G1_LDB(0, 3, b1_);                           \
    if (DO_STAGE) G1_STAGE_B((t) + 1, 0);                           \
    BAR; LGKM0; SB0;                                                \
    G1_MFMA(b0_, b1_, 2, 3);                                        \
    W2; BAR;                                                        \
    G1_LDA(1); G1_LDB(1, 0, b0_); G1_LDB(1, 1, b1_);                \
    if (DO_STAGE) G1_STAGE_A((t) + 1, 1);                           \
    BAR; LGKM0; SB0;                                                \
    G1_MFMA(b0_, b1_, 0, 1);                                        \
    BAR;                                                            \
    G1_LDB(1, 2, b0_); G1_LDB(1, 3, b1_);                           \
    if (DO_STAGE) G1_STAGE_B((t) + 1, 1);                           \
    BAR; LGKM0; SB0;                                                \
    G1_MFMA(b0_, b1_, 2, 3);                                        \
    W4; BAR;                                                        \
  }

template <int NX, int NY>
__global__ __launch_bounds__(512, 2) void gemm1_kernel(
    const u16* __restrict__ xg, const u16* __restrict__ w1tB,
    const int* __restrict__ counts, u16* __restrict__ hB,
    const float* __restrict__ b1, int e0, long long hStrideE) {
  extern __shared__ __align__(16) u16 smem[];  // 65536 u16 = 128 KB
  int bx, by, bz;
  tile_coords<NX, NY>(bx, by, bz);
  int e = e0 + bz;
  int m0 = by * 256, n0 = bx * 256;
  if (m0 >= counts[e]) return;
  const u16* Bg = w1tB + (size_t)e * FDIM * DMODEL;
  u16* H = hB + (size_t)bz * hStrideE;
  int tid = threadIdx.x;

  const u16* paA = xg + (size_t)(e * CAP + m0 + (tid >> 2)) * DMODEL +
                   (tid & 3) * 8;
  const u16* paB = Bg + (size_t)n0 * 32 + tid * 8;

  int wid = tid >> 6, lane = tid & 63;
  int wm = (wid >> 2) * 128, wn = (wid & 3) * 64;
  int fr = lane & 15, fk = (lane >> 4) * 8;
  int aoff = (wm + fr) * 32 + fk;
  int boff = (wn + fr) * 32 + fk;
  f32x4 acc[8][4] = {};

  // prologue: stage step 0 (A-kk0, B-kk0, A-kk1, B-kk1); wait first 4 loads
  G1_STAGE_A(0, 0);
  G1_STAGE_B(0, 0);
  G1_STAGE_A(0, 1);
  G1_STAGE_B(0, 1);
  VMWAIT(4);
  BAR;

  const int KT = DMODEL / 64;  // 16 K-steps
#pragma unroll 1
  for (int t = 0; t < KT - 1; ++t) G1_STEP(t, true, VMWAIT(4), VMWAIT(4));
  G1_STEP(KT - 1, false, VMWAIT(0), (void)0);

  // epilogue: bias + GELU -> swizzled 256x256 bf16 LDS image (128 KB exact)
  int fq = lane >> 4;
  const float* b1g = b1 + (size_t)e * FDIM + n0;
  float bias[4];
#pragma unroll
  for (int n = 0; n < 4; n++) bias[n] = b1g[wn + n * 16 + fr];
#pragma unroll
  for (int m = 0; m < 8; m++) {
#pragma unroll
    for (int n = 0; n < 4; n++) {
      int colL = wn + n * 16 + fr;  // 0..255
#pragma unroll
      for (int j = 0; j < 4; j++) {
        int rL = wm + m * 16 + fq * 4 + j;  // 0..255
        float v = gelu_exact(acc[m][n][j] + bias[n]);
        int ch = (colL >> 3) ^ ((rL >> 2) & 7);
        smem[rL * 256 + ch * 8 + (colL & 7)] = f2bf(v);
      }
    }
  }
  __syncthreads();
#pragma unroll
  for (int p = 0; p < 16; p++) {
    int idx = p * 512 + tid;
    int rr = idx >> 5, cch = idx & 31;
    int ch = cch ^ ((rr >> 2) & 7);
    short8 v = *(const short8*)(smem + rr * 256 + ch * 8);
    *(short8*)(H + (size_t)(m0 + rr) * FDIM + n0 + cch * 8) = v;
  }
}

// ======= GEMM2: 128x128, BK=64 (2x [128][32]), same 4-phase schedule =========
// 256 thr = 4 waves 2M x 2N (per-wave 64x64, acc[4][4]). LDS 64KB, 2 blk/CU.
#define G2_STAGE_A(t, kk)                                           \
  {                                                                 \
    u16* d_ = smem + ((t)&1) * 16384 + (kk)*4096 + tid * 8;         \
    const u16* s_ = paA + (size_t)(t)*64 + (kk)*32;                 \
    gload_lds16(s_, d_);                                            \
    gload_lds16(s_ + (size_t)64 * FDIM, d_ + 2048);                 \
  }
#define G2_STAGE_B(t, kk)                                           \
  {                                                                 \
    u16* d_ = smem + ((t)&1) * 16384 + 8192 + (kk)*4096 + tid * 8;  \
    const u16* s_ = paB + (size_t)(2 * (t) + (kk)) * (DMODEL * 32); \
    gload_lds16(s_, d_);                                            \
    gload_lds16(s_ + 2048, d_ + 2048);                              \
  }
#define G2_LDA(kk)                                                  \
  _Pragma("unroll") for (int m_ = 0; m_ < 4; m_++) a_[m_] =         \
      *(const short8*)(smem + bufo + (kk)*4096 + aoff + m_ * 512);
#define G2_LDB(kk, n, dst)                                          \
  dst = *(const short8*)(smem + bufo + 8192 + (kk)*4096 + boff + (n)*512);
#define G2_MFMA(B0, B1, c0, c1)                                             \
  __builtin_amdgcn_s_setprio(1);                                            \
  _Pragma("unroll") for (int m_ = 0; m_ < 4; m_++) {                        \
    acc[m_][c0] = __builtin_amdgcn_mfma_f32_16x16x32_bf16(a_[m_], B0,       \
                                                          acc[m_][c0], 0,   \
                                                          0, 0);            \
    acc[m_][c1] = __builtin_amdgcn_mfma_f32_16x16x32_bf16(a_[m_], B1,       \
                                                          acc[m_][c1], 0,   \
                                                          0, 0);            \
  }                                                                         \
  __builtin_amdgcn_s_setprio(0);

#define G2_STEP(t, DO_STAGE, W2, W4)                                \
  {                                                                 \
    const int bufo = ((t)&1) * 16384;                               \
    short8 a_[4], b0_, b1_;                                         \
    G2_LDA(0); G2_LDB(0, 0, b0_); G2_LDB(0, 1, b1_);                \
    if (DO_STAGE) G2_STAGE_A((t) + 1, 0);                           \
    BAR; LGKM0; SB0;                                                \
    G2_MFMA(b0_, b1_, 0, 1);                                        \
    BAR;                                                            \
    G2_LDB(0, 2, b0_); G2_LDB(0, 3, b1_);                           \
    if (DO_STAGE) G2_STAGE_B((t) + 1, 0);                           \
    BAR; LGKM0; SB0;                                                \
    G2_MFMA(b0_, b1_, 2, 3);                                        \
    W2; BAR;                                                        \
    G2_LDA(1); G2_LDB(1, 0, b0_); G2_LDB(1, 1, b1_);                \
    if (DO_STAGE) G2_STAGE_A((t) + 1, 1);                           \
    BAR; LGKM0; SB0;                                                \
    G2_MFMA(b0_, b1_, 0, 1);                                        \
    BAR;                                                            \
    G2_LDB(1, 2, b0_); G2_LDB(1, 3, b1_);                           \
    if (DO_STAGE) G2_STAGE_B((t) + 1, 1);                           \
    BAR; LGKM0; SB0;                                                \
    G2_MFMA(b0_, b1_, 2, 3);                                        \
    W4; BAR;                                                        \
  }

template <int NX, int NY>
__global__ __launch_bounds__(256, 2) void gemm2_kernel(
    const u16* __restrict__ hB, const u16* __restrict__ w2tB,
    float* __restrict__ out, const float* __restrict__ b2,
    const int* __restrict__ tok_of_slot, const int* __restrict__ counts,
    const float* __restrict__ chosen_p, int e0, long long hStrideE) {
  extern __shared__ __align__(16) u16 smem[];  // 32768 u16 = 64 KB
  int bx, by, bz;
  tile_coords<NX, NY>(bx, by, bz);
  int e = e0 + bz;
  int m0 = by * 128, n0 = bx * 128;
  if (m0 >= counts[e]) return;
  const u16* Ag = hB + (size_t)bz * hStrideE;
  const u16* Bg = w2tB + (size_t)e * DMODEL * FDIM;
  const float* b2g = b2 + (size_t)e * DMODEL;
  int tid = threadIdx.x;

  const u16* paA = Ag + (size_t)(m0 + (tid >> 2)) * FDIM + (tid & 3) * 8;
  const u16* paB = Bg + (size_t)n0 * 32 + tid * 8;

  int wid = tid >> 6, lane = tid & 63;
  int wm = (wid >> 1) * 64, wn = (wid & 1) * 64;
  int fr = lane & 15, fk = (lane >> 4) * 8;
  int aoff = (wm + fr) * 32 + fk;
  int boff = (wn + fr) * 32 + fk;
  f32x4 acc[4][4] = {};

  G2_STAGE_A(0, 0);
  G2_STAGE_B(0, 0);
  G2_STAGE_A(0, 1);
  G2_STAGE_B(0, 1);
  VMWAIT(4);
  BAR;

  const int KT = FDIM / 64;  // 64 K-steps
#pragma unroll 1
  for (int t = 0; t < KT - 1; ++t) G2_STEP(t, true, VMWAIT(4), VMWAIT(4));
  G2_STEP(KT - 1, false, VMWAIT(0), (void)0);

  int fq = lane >> 4;
  float bias[4];
#pragma unroll
  for (int n = 0; n < 4; n++) bias[n] = b2g[n0 + wn + n * 16 + fr];
#pragma unroll
  for (int m = 0; m < 4; m++) {
#pragma unroll
    for (int j = 0; j < 4; j++) {
      int rL = wm + m * 16 + fq * 4 + j;
      int tk = tok_of_slot[e * CAP + m0 + rL];
      if (tk >= 0) {
        float sc = chosen_p[tk];
#pragma unroll
        for (int n = 0; n < 4; n++) {
          int colL = wn + n * 16 + fr;
          out[(size_t)tk * DMODEL + n0 + colL] = (acc[m][n][j] + bias[n]) * sc;
        }
      }
    }
  }
}

extern "C" void kernel_launch(void* const* d_in, const int* in_sizes, int n_in,
                              void* d_out, int out_size, void* d_ws,
                              size_t ws_size, hipStream_t stream) {
  const float* x = (const float*)d_in[0];
  const float* rw = (const float*)d_in[1];
  const float* w1 = (const float*)d_in[2];
  const float* b1 = (const float*)d_in[3];
  const float* w2 = (const float*)d_in[4];
  const float* b2 = (const float*)d_in[5];
  float* out = (float*)d_out;

  char* ws = (char*)d_ws;
  size_t off = 0;
  auto alloc = [&](size_t bytes) -> void* {
    void* p = ws + off;
    off = (off + bytes + 255) & ~(size_t)255;
    return p;
  };
  int* chosen_e = (int*)alloc((size_t)NTOK * 4);
  float* chosen_p = (float*)alloc((size_t)NTOK * 4);
  int* tok_of_slot = (int*)alloc((size_t)NEXP * CAP * 4);
  int* counts = (int*)alloc(NEXP * 4);
  u16* xg = (u16*)alloc((size_t)NEXP * CAP * DMODEL * 2);
  u16* w1t = (u16*)alloc((size_t)NEXP * DMODEL * FDIM * 2);
  u16* w2t = (u16*)alloc((size_t)NEXP * DMODEL * FDIM * 2);
  size_t hFull = (size_t)NEXP * CAP * FDIM * 2;
  size_t hLoop = (size_t)CAP * FDIM * 2;
  bool full = (off + hFull) <= ws_size;
  u16* h = (u16*)alloc(full ? hFull : hLoop);

  static_assert(CAP % 256 == 0 && FDIM % 256 == 0 && DMODEL % 128 == 0, "");
  const int TLDS = 131072, G1LDS = 131072, G2LDS = 65536;
  hipFuncSetAttribute((const void*)wtrans_kernel,
                      hipFuncAttributeMaxDynamicSharedMemorySize, TLDS);
  hipFuncSetAttribute((const void*)gemm1_kernel<FDIM / 256, CAP / 256>,
                      hipFuncAttributeMaxDynamicSharedMemorySize, G1LDS);
  hipFuncSetAttribute((const void*)gemm2_kernel<DMODEL / 128, CAP / 128>,
                      hipFuncAttributeMaxDynamicSharedMemorySize, G2LDS);

  router_kernel<<<NTOK / 4, 256, 0, stream>>>(x, rw, chosen_e, chosen_p);
  wtrans_kernel<<<1025, 1024, TLDS, stream>>>(w1, w2, w1t, w2t, chosen_e,
                                              tok_of_slot, counts, out);
  gather_kernel<<<NEXP * CAP / 4, 256, 0, stream>>>(x, tok_of_slot, xg);

  if (full) {
    gemm1_kernel<FDIM / 256, CAP / 256>
        <<<dim3(FDIM / 256, CAP / 256, NEXP), 512, G1LDS, stream>>>(
            xg, w1t, counts, h, b1, 0, (long long)CAP * FDIM);
    gemm2_kernel<DMODEL / 128, CAP / 128>
        <<<dim3(DMODEL / 128, CAP / 128, NEXP), 256, G2LDS, stream>>>(
            h, w2t, out, b2, tok_of_slot, counts, chosen_p, 0,
            (long long)CAP * FDIM);
  } else {
    for (int e = 0; e < NEXP; e++) {
      gemm1_kernel<FDIM / 256, CAP / 256>
          <<<dim3(FDIM / 256, CAP / 256, 1), 512, G1LDS, stream>>>(
              xg, w1t, counts, h, b1, e, 0);
      gemm2_kernel<DMODEL / 128, CAP / 128>
          <<<dim3(DMODEL / 128, CAP / 128, 1), 256, G2LDS, stream>>>(
              h, w2t, out, b2, tok_of_slot, counts, chosen_p, e, 0);
    }
  }
  (void)in_sizes;
  (void)n_in;
  (void)ws_size;
}

// Round 5
// 321.457 us; speedup vs baseline: 1.3351x; 1.1683x over previous
//
#include <hip/hip_runtime.h>
#include <hip/hip_bf16.h>
#include <math.h>

typedef unsigned short u16;
typedef __attribute__((ext_vector_type(8))) short short8;
typedef __attribute__((ext_vector_type(4))) float f32x4;

#define NTOK 8192
#define DMODEL 1024
#define FDIM 4096
#define NEXP 8
#define CAP 1536

__device__ __forceinline__ u16 f2bf(float f) {
  __hip_bfloat16 b = __float2bfloat16(f);
  u16 u;
  __builtin_memcpy(&u, &b, 2);
  return u;
}

// branchless exact-erf GELU (Abramowitz-Stegun 7.1.26, |err| <= 1.5e-7)
__device__ __forceinline__ float gelu_exact(float v) {
  float x = v * 0.70710678118654752f;
  float ax = fabsf(x);
  float t = __builtin_amdgcn_rcpf(1.0f + 0.3275911f * ax);
  float p =
      t * (0.254829592f +
           t * (-0.284496736f +
                t * (1.421413741f + t * (-1.453152027f + t * 1.061405429f))));
  float er = 1.0f - p * __expf(-ax * ax);
  er = copysignf(er, x);
  return 0.5f * v * (1.0f + er);
}

// async global->LDS DMA, 16B/lane. LDS dest = wave-uniform base + lane*16;
// global source address is per-lane (enables gathered staging).
__device__ __forceinline__ void gload_lds16(const u16* g, u16* l) {
  __builtin_amdgcn_global_load_lds(
      (const __attribute__((address_space(1))) void*)g,
      (__attribute__((address_space(3))) void*)l, 16, 0, 0);
}

// ===== K1: x fp32->bf16 cast + router ========================================
// blocks [0,4096): x cast; [4096,6144): router (4 tokens/block, 1 wave/token)
__global__ __launch_bounds__(256) void router_cast_kernel(
    const float* __restrict__ x, const float* __restrict__ rw,
    u16* __restrict__ xbf, int* __restrict__ chosen_e,
    float* __restrict__ chosen_p) {
  int b = blockIdx.x, tid = threadIdx.x;
  if (b < 4096) {
    size_t base = (size_t)b * 2048 + tid * 8;
    float4 v0 = *(const float4*)(x + base);
    float4 v1 = *(const float4*)(x + base + 4);
    short8 sv;
    sv[0] = (short)f2bf(v0.x); sv[1] = (short)f2bf(v0.y);
    sv[2] = (short)f2bf(v0.z); sv[3] = (short)f2bf(v0.w);
    sv[4] = (short)f2bf(v1.x); sv[5] = (short)f2bf(v1.y);
    sv[6] = (short)f2bf(v1.z); sv[7] = (short)f2bf(v1.w);
    *(short8*)(xbf + base) = sv;
  } else {
    int tok = ((b - 4096) * 256 + tid) >> 6;
    int lane = tid & 63;
    const float4* xp = (const float4*)(x + (size_t)tok * DMODEL) + lane * 4;
    float4 x0 = xp[0], x1 = xp[1], x2 = xp[2], x3 = xp[3];
    float l[8];
#pragma unroll
    for (int e = 0; e < 8; e++) {
      const float4* wp = (const float4*)(rw + (size_t)e * DMODEL) + lane * 4;
      float4 w0 = wp[0], w1v = wp[1], w2v = wp[2], w3 = wp[3];
      float s = x0.x * w0.x + x0.y * w0.y + x0.z * w0.z + x0.w * w0.w;
      s += x1.x * w1v.x + x1.y * w1v.y + x1.z * w1v.z + x1.w * w1v.w;
      s += x2.x * w2v.x + x2.y * w2v.y + x2.z * w2v.z + x2.w * w2v.w;
      s += x3.x * w3.x + x3.y * w3.y + x3.z * w3.z + x3.w * w3.w;
      l[e] = s;
    }
#pragma unroll
    for (int off = 32; off > 0; off >>= 1) {
#pragma unroll
      for (int e = 0; e < 8; e++) l[e] += __shfl_xor(l[e], off, 64);
    }
    if (lane == 0) {
      float best = l[0];
      int am = 0;
#pragma unroll
      for (int e = 1; e < 8; e++)
        if (l[e] > best) { best = l[e]; am = e; }
      float denom = 0.f;
#pragma unroll
      for (int e = 0; e < 8; e++) denom += expf(l[e] - best);
      chosen_e[tok] = am;
      chosen_p[tok] = 1.0f / denom;
    }
  }
}

// 256x256 fp32->bf16 transpose tile through swizzled LDS, 1024 threads.
__device__ __forceinline__ void trans256(const float* __restrict__ ip,
                                         u16* __restrict__ op, int Rin,
                                         int Cin, int r0, int c0, char* lds,
                                         int tid) {
  int w = tid >> 6, l = tid & 63;
#pragma unroll
  for (int i = 0; i < 16; i++) {
    int row = w * 16 + i;
    float4 v = *(const float4*)(ip + (size_t)(r0 + row) * Cin + c0 + l * 4);
    uint2 d;
    d.x = (unsigned)f2bf(v.x) | ((unsigned)f2bf(v.y) << 16);
    d.y = (unsigned)f2bf(v.z) | ((unsigned)f2bf(v.w) << 16);
    int ch = (l >> 1) ^ ((row >> 3) & 7);
    *(uint2*)(lds + row * 512 + ch * 16 + (l & 1) * 8) = d;
  }
  __syncthreads();
#pragma unroll
  for (int p = 0; p < 2; p++) {
    int c = ((tid >> 5) + p * 32) * 4;
    int rb = (tid & 31) * 8;
    short8 s0, s1, s2, s3;
#pragma unroll
    for (int j = 0; j < 8; j++) {
      int r = rb + j;
      int ch = (c >> 3) ^ ((r >> 3) & 7);
      uint2 d = *(const uint2*)(lds + r * 512 + ch * 16 + (c & 7) * 2);
      s0[j] = (short)(d.x & 0xffff);
      s1[j] = (short)(d.x >> 16);
      s2[j] = (short)(d.y & 0xffff);
      s3[j] = (short)(d.y >> 16);
    }
    u16* ob = op + (size_t)(c0 + c) * Rin + r0 + rb;
    *(short8*)(ob) = s0;
    *(short8*)(ob + (size_t)Rin) = s1;
    *(short8*)(ob + 2 * (size_t)Rin) = s2;
    *(short8*)(ob + 3 * (size_t)Rin) = s3;
  }
}

// ===== K2: scan (block 0) + w1/w2 transpose (blocks 1..1024) ================
__global__ __launch_bounds__(1024, 1) void wtrans_kernel(
    const float* __restrict__ w1, const float* __restrict__ w2,
    u16* __restrict__ w1t, u16* __restrict__ w2t,
    const int* __restrict__ chosen_e, int* __restrict__ tok_of_slot,
    int* __restrict__ counts, float* __restrict__ out) {
  extern __shared__ char lds[];
  int b = blockIdx.x, tid = threadIdx.x;
  if (b == 0) {
    if (tid < 512) {
      int w = tid >> 6, lane = tid & 63;
      unsigned long long ltmask =
          (lane == 63) ? ~0ull >> 1 : (1ull << lane) - 1ull;
      int cnt = 0;
      for (int c = 0; c < NTOK / 64; c++) {
        int i = c * 64 + lane;
        int e = chosen_e[i];
        unsigned long long bal = __ballot(e == w);
        if (e == w) {
          int p = cnt + __popcll(bal & ltmask);
          if (p < CAP) {
            tok_of_slot[w * CAP + p] = i;
          } else {  // dropped token: its out row must be zero (no memset)
            float4 z = make_float4(0.f, 0.f, 0.f, 0.f);
            float* orow = out + (size_t)i * DMODEL;
            for (int d = 0; d < DMODEL; d += 4) *(float4*)(orow + d) = z;
          }
        }
        cnt += __popcll(bal);
      }
      for (int p = cnt + lane; p < CAP; p += 64) tok_of_slot[w * CAP + p] = -1;
      if (lane == 0) counts[w] = cnt < CAP ? cnt : CAP;
    }
  } else if (b < 513) {
    int idx = b - 1;
    int e = idx >> 6, rem = idx & 63;  // D/256=4 x F/256=16 tiles
    int r0 = (rem >> 4) * 256, c0 = (rem & 15) * 256;
    trans256(w1 + (size_t)e * DMODEL * FDIM, w1t + (size_t)e * DMODEL * FDIM,
             DMODEL, FDIM, r0, c0, lds, tid);
  } else {
    int idx = b - 513;
    int e = idx >> 6, rem = idx & 63;  // F/256=16 x D/256=4 tiles
    int r0 = (rem >> 2) * 256, c0 = (rem & 3) * 256;
    trans256(w2 + (size_t)e * DMODEL * FDIM, w2t + (size_t)e * DMODEL * FDIM,
             FDIM, DMODEL, r0, c0, lds, tid);
  }
}

// ---------------- XCD-aware bijective tile swizzle (nwg % 8 == 0) ------------
template <int NX, int NY>
__device__ __forceinline__ void tile_coords(int& bx, int& by, int& bz) {
  int flat = blockIdx.x + NX * (blockIdx.y + NY * blockIdx.z);
  int nwg = NX * NY * (int)gridDim.z;
  int swz = (flat & 7) * (nwg >> 3) + (flat >> 3);
  bx = swz % NX;
  int rem = swz / NX;
  by = rem % NY;
  bz = rem / NY;
}

// ====== 128x128 BK=32 double-buffered 2-phase mainloop (m97 structure) =======
// 256 thr = 4 waves 2M x 2N (per-wave 64x64, acc[4][4]). LDS 32KB dbuf.
template <int KD>
__device__ __forceinline__ void mainloop_db(const u16* pa0, const u16* pa1,
                                            const u16* pb0, const u16* pb1,
                                            u16* smem, f32x4 (&acc)[4][4],
                                            int tid) {
  int wid = tid >> 6, lane = tid & 63;
  int wm = (wid >> 1) * 64, wn = (wid & 1) * 64;
  int fr = lane & 15, fk = (lane >> 4) * 8;
  int aro = (wm + fr) * 32 + fk;
  int bro = 4096 + (wn + fr) * 32 + fk;
  gload_lds16(pa0, smem + tid * 8);
  gload_lds16(pa1, smem + 2048 + tid * 8);
  gload_lds16(pb0, smem + 4096 + tid * 8);
  gload_lds16(pb1, smem + 6144 + tid * 8);
  __syncthreads();
  int cur = 0;
#pragma unroll 1
  for (int t = 0; t < KD / 32; ++t) {
    const u16* cb = smem + cur * 8192;
    u16* nb = smem + (cur ^ 1) * 8192;
    if (t + 1 < KD / 32) {
      int k = (t + 1) * 32;
      gload_lds16(pa0 + k, nb + tid * 8);
      gload_lds16(pa1 + k, nb + 2048 + tid * 8);
      gload_lds16(pb0 + k, nb + 4096 + tid * 8);
      gload_lds16(pb1 + k, nb + 6144 + tid * 8);
    }
    short8 av[4], bv[4];
#pragma unroll
    for (int m = 0; m < 4; m++) av[m] = *(const short8*)(cb + aro + m * 512);
#pragma unroll
    for (int n = 0; n < 4; n++) bv[n] = *(const short8*)(cb + bro + n * 512);
#pragma unroll
    for (int m = 0; m < 4; m++)
#pragma unroll
      for (int n = 0; n < 4; n++)
        acc[m][n] = __builtin_amdgcn_mfma_f32_16x16x32_bf16(av[m], bv[n],
                                                            acc[m][n], 0, 0, 0);
    __syncthreads();
    cur ^= 1;
  }
}

// ------- GEMM1: 128x128 tile (m97 geometry), gather(xbf) @ w1t^T -> GELU -----
// 2048 active blocks (8/CU, multi-round residency for TLP latency hiding).
// Epilogue: bias+GELU -> swizzled 128x128 bf16 LDS image -> coalesced stores.
template <int NX, int NY>
__global__ __launch_bounds__(256) void gemm1_kernel(
    const u16* __restrict__ xbf, const u16* __restrict__ w1tB,
    const int* __restrict__ tok_of_slot, const int* __restrict__ counts,
    u16* __restrict__ hB, const float* __restrict__ b1, int e0,
    long long hStrideE) {
  __shared__ __align__(16) u16 smem[16384];  // 32KB: dbuf, then C-image
  int bx, by, bz;
  tile_coords<NX, NY>(bx, by, bz);
  int e = e0 + bz;
  int m0 = by * 128, n0 = bx * 128;
  if (m0 >= counts[e]) return;  // slots [counts,CAP) are never gathered
  const u16* Bg = w1tB + (size_t)e * FDIM * DMODEL;
  u16* H = hB + (size_t)bz * hStrideE;
  const float* b1g = b1 + (size_t)e * FDIM;
  int tid = threadIdx.x;
  int r2 = tid >> 2, c8 = (tid & 3) * 8;
  int t0 = tok_of_slot[e * CAP + m0 + r2];
  t0 &= ~(t0 >> 31);
  int t1 = tok_of_slot[e * CAP + m0 + 64 + r2];
  t1 &= ~(t1 >> 31);
  const u16* pa0 = xbf + (size_t)t0 * DMODEL + c8;
  const u16* pa1 = xbf + (size_t)t1 * DMODEL + c8;
  const u16* pb0 = Bg + (size_t)(n0 + r2) * DMODEL + c8;
  const u16* pb1 = pb0 + (size_t)64 * DMODEL;
  f32x4 acc[4][4] = {};
  mainloop_db<DMODEL>(pa0, pa1, pb0, pb1, smem, acc, tid);

  // epilogue: bias + exact GELU -> swizzled LDS image -> coalesced H stores
  int wid = tid >> 6, lane = tid & 63;
  int wm = (wid >> 1) * 64, wn = (wid & 1) * 64;
  int fr = lane & 15, fq = lane >> 4;
  float bias[4];
#pragma unroll
  for (int n = 0; n < 4; n++) bias[n] = b1g[n0 + wn + n * 16 + fr];
#pragma unroll
  for (int m = 0; m < 4; m++) {
#pragma unroll
    for (int n = 0; n < 4; n++) {
      int colL = wn + n * 16 + fr;  // 0..127
#pragma unroll
      for (int j = 0; j < 4; j++) {
        int rL = wm + m * 16 + fq * 4 + j;  // 0..127
        float v = gelu_exact(acc[m][n][j] + bias[n]);
        int ch = (colL >> 3) ^ ((rL >> 2) & 7);
        smem[rL * 128 + ch * 8 + (colL & 7)] = f2bf(v);
      }
    }
  }
  __syncthreads();
#pragma unroll
  for (int p = 0; p < 8; p++) {
    int idx = p * 256 + tid;
    int rr = idx >> 4, cch = idx & 15;
    int ch = cch ^ ((rr >> 2) & 7);
    short8 v = *(const short8*)(smem + rr * 128 + ch * 8);
    *(short8*)(H + (size_t)(m0 + rr) * FDIM + n0 + cch * 8) = v;
  }
}

// ---------------- GEMM2: h @ w2t^T + b2, fused gather+scale into out ---------
template <int NX, int NY>
__global__ __launch_bounds__(256) void gemm2_kernel(
    const u16* __restrict__ hB, const u16* __restrict__ w2tB,
    float* __restrict__ out, const float* __restrict__ b2,
    const int* __restrict__ tok_of_slot, const int* __restrict__ counts,
    const float* __restrict__ chosen_p, int e0, long long hStrideE) {
  __shared__ __align__(16) u16 smem[16384];  // 32KB dbuf
  int bx, by, bz;
  tile_coords<NX, NY>(bx, by, bz);
  int e = e0 + bz;
  int m0 = by * 128, n0 = bx * 128;
  if (m0 >= counts[e]) return;  // same exit condition as gemm1
  const u16* Ag = hB + (size_t)bz * hStrideE;
  const u16* Bg = w2tB + (size_t)e * DMODEL * FDIM;
  const float* b2g = b2 + (size_t)e * DMODEL;
  int tid = threadIdx.x;
  int r2 = tid >> 2, c8 = (tid & 3) * 8;
  const u16* pa0 = Ag + (size_t)(m0 + r2) * FDIM + c8;
  const u16* pa1 = pa0 + (size_t)64 * FDIM;
  const u16* pb0 = Bg + (size_t)(n0 + r2) * FDIM + c8;
  const u16* pb1 = pb0 + (size_t)64 * FDIM;
  f32x4 acc[4][4] = {};
  mainloop_db<FDIM>(pa0, pa1, pb0, pb1, smem, acc, tid);

  int wid = tid >> 6, lane = tid & 63;
  int wm = (wid >> 1) * 64, wn = (wid & 1) * 64;
  int fr = lane & 15, fq = lane >> 4;
  float bias[4];
#pragma unroll
  for (int n = 0; n < 4; n++) bias[n] = b2g[n0 + wn + n * 16 + fr];
#pragma unroll
  for (int m = 0; m < 4; m++) {
#pragma unroll
    for (int j = 0; j < 4; j++) {
      int rL = wm + m * 16 + fq * 4 + j;
      int tk = tok_of_slot[e * CAP + m0 + rL];
      if (tk >= 0) {
        float sc = chosen_p[tk];
#pragma unroll
        for (int n = 0; n < 4; n++) {
          int colL = wn + n * 16 + fr;
          out[(size_t)tk * DMODEL + n0 + colL] = (acc[m][n][j] + bias[n]) * sc;
        }
      }
    }
  }
}

extern "C" void kernel_launch(void* const* d_in, const int* in_sizes, int n_in,
                              void* d_out, int out_size, void* d_ws,
                              size_t ws_size, hipStream_t stream) {
  const float* x = (const float*)d_in[0];
  const float* rw = (const float*)d_in[1];
  const float* w1 = (const float*)d_in[2];
  const float* b1 = (const float*)d_in[3];
  const float* w2 = (const float*)d_in[4];
  const float* b2 = (const float*)d_in[5];
  float* out = (float*)d_out;

  char* ws = (char*)d_ws;
  size_t off = 0;
  auto alloc = [&](size_t bytes) -> void* {
    void* p = ws + off;
    off = (off + bytes + 255) & ~(size_t)255;
    return p;
  };
  int* chosen_e = (int*)alloc((size_t)NTOK * 4);
  float* chosen_p = (float*)alloc((size_t)NTOK * 4);
  int* tok_of_slot = (int*)alloc((size_t)NEXP * CAP * 4);
  int* counts = (int*)alloc(NEXP * 4);
  u16* xbf = (u16*)alloc((size_t)NTOK * DMODEL * 2);
  u16* w1t = (u16*)alloc((size_t)NEXP * DMODEL * FDIM * 2);
  u16* w2t = (u16*)alloc((size_t)NEXP * DMODEL * FDIM * 2);
  size_t hFull = (size_t)NEXP * CAP * FDIM * 2;
  size_t hLoop = (size_t)CAP * FDIM * 2;
  bool full = (off + hFull) <= ws_size;
  u16* h = (u16*)alloc(full ? hFull : hLoop);

  static_assert(CAP % 128 == 0 && FDIM % 128 == 0 && DMODEL % 128 == 0, "");
  const int TLDS = 131072;
  hipFuncSetAttribute((const void*)wtrans_kernel,
                      hipFuncAttributeMaxDynamicSharedMemorySize, TLDS);

  router_cast_kernel<<<4096 + NTOK / 4, 256, 0, stream>>>(x, rw, xbf, chosen_e,
                                                          chosen_p);
  wtrans_kernel<<<1025, 1024, TLDS, stream>>>(w1, w2, w1t, w2t, chosen_e,
                                              tok_of_slot, counts, out);

  if (full) {
    gemm1_kernel<FDIM / 128, CAP / 128>
        <<<dim3(FDIM / 128, CAP / 128, NEXP), 256, 0, stream>>>(
            xbf, w1t, tok_of_slot, counts, h, b1, 0, (long long)CAP * FDIM);
    gemm2_kernel<DMODEL / 128, CAP / 128>
        <<<dim3(DMODEL / 128, CAP / 128, NEXP), 256, 0, stream>>>(
            h, w2t, out, b2, tok_of_slot, counts, chosen_p, 0,
            (long long)CAP * FDIM);
  } else {
    for (int e = 0; e < NEXP; e++) {
      gemm1_kernel<FDIM / 128, CAP / 128>
          <<<dim3(FDIM / 128, CAP / 128, 1), 256, 0, stream>>>(
              xbf, w1t, tok_of_slot, counts, h, b1, e, 0);
      gemm2_kernel<DMODEL / 128, CAP / 128>
          <<<dim3(DMODEL / 128, CAP / 128, 1), 256, 0, stream>>>(
              h, w2t, out, b2, tok_of_slot, counts, chosen_p, e, 0);
    }
  }
  (void)in_sizes;
  (void)n_in;
  (void)ws_size;
}